// Round 2
// baseline (386.006 us; speedup 1.0000x reference)
//
#include <hip/hip_runtime.h>
#include <hip/hip_bf16.h>
#include <math.h>

#define NB 4
#define NL 512
#define ND 128
#define KSTR 136  // 128 + 8 bf16 pad -> 272B row stride, 16B aligned, 2-way banks (free)

typedef __attribute__((ext_vector_type(8))) short bf16x8;
typedef __attribute__((ext_vector_type(4))) float f32x4;

__device__ __forceinline__ short f2bf(float f) {
  union { float f; unsigned u; } un; un.f = f;
  unsigned r = un.u + 0x7FFFu + ((un.u >> 16) & 1u);  // RNE
  return (short)(r >> 16);
}

// exact-GELU via Abramowitz-Stegun 7.1.26 erf (max err 1.5e-7), branchless:
// 1 v_rcp + 1 v_exp + ~14 VALU vs libm erff's ~35+ with branches.
__device__ __forceinline__ float gelu_exact(float h) {
  const float z = 0.70710678118f * h;
  const float az = fabsf(z);
  const float t = __builtin_amdgcn_rcpf(fmaf(0.3275911f, az, 1.0f));
  float p = fmaf(1.061405429f, t, -1.453152027f);
  p = fmaf(p, t, 1.421413741f);
  p = fmaf(p, t, -0.284496736f);
  p = fmaf(p, t, 0.254829592f);
  p = p * t;
  const float ex = exp2f(az * az * -1.4426950408f);  // e^{-z^2}
  const float e = fmaf(-p, ex, 1.0f);                // erf(|z|)
  const float se = copysignf(e, z);
  const float hh = 0.5f * h;
  return fmaf(hh, se, hh);                            // 0.5h(1+erf(z))
}

// one-time weight prep into d_ws: gamma-folded bf16 w1 [n][k], beta-folded b1,
// notpad floats, per-batch 1/atom_num
__global__ void unimol_prep(const float* __restrict__ w1, const float* __restrict__ ln_g,
                            const float* __restrict__ ln_b, const float* __restrict__ b1,
                            const int* __restrict__ nodes,
                            short* __restrict__ w1f, float* __restrict__ b1p,
                            float* __restrict__ npad, float* __restrict__ inva) {
  const int tid = threadIdx.x;
  for (int idx = tid; idx < ND * ND; idx += 256) {
    const int k = idx >> 7, n = idx & (ND - 1);
    w1f[n * ND + k] = f2bf(w1[idx] * ln_g[k]);
  }
  if (tid < ND) {
    float s = b1[tid];
    for (int k = 0; k < ND; ++k) s = fmaf(ln_b[k], w1[k * ND + tid], s);
    b1p[tid] = s;
  }
  for (int j = tid; j < NB * NL; j += 256) npad[j] = (nodes[j] != 0) ? 1.0f : 0.0f;
  const int wv = tid >> 6, lane = tid & 63;
  if (wv < NB) {
    float s = 0.f;
    for (int j = lane; j < NL; j += 64) s += (nodes[wv * NL + j] != 0) ? 1.0f : 0.0f;
    #pragma unroll
    for (int m = 1; m <= 32; m <<= 1) s += __shfl_xor(s, m);
    if (lane == 0) inva[wv] = 1.0f / s;
  }
}

template <bool PREP>
__global__ __launch_bounds__(256, 3) void unimol_coord_head(
    const float* __restrict__ x, const float* __restrict__ coord,
    const int* __restrict__ nodes, const float* __restrict__ ln_g,
    const float* __restrict__ ln_b, const float* __restrict__ w1,
    const float* __restrict__ b1, const float* __restrict__ w2,
    const float* __restrict__ b2,
    const short* __restrict__ w1f, const float* __restrict__ b1pw,
    const float* __restrict__ npadw, const float* __restrict__ invw,
    float* __restrict__ out)
{
  __shared__ __align__(16) short w1T[ND * KSTR];  // [n][k] bf16, gamma-folded
  __shared__ float b1p[ND];
  __shared__ float notpad[NL];
  __shared__ float coord_s[NL * 3];
  __shared__ float red[16];
  __shared__ float inv_atom_s;

  const int blk = blockIdx.x;
  const int bb = blk >> 9;
  const int lrow = blk & (NL - 1);
  const int tid = threadIdx.x;

  // pad row l: output = coord, contribution zero
  if (nodes[bb * NL + lrow] == 0) {
    if (tid < 3) out[(bb * NL + lrow) * 3 + tid] = coord[(bb * NL + lrow) * 3 + tid];
    return;
  }

  // ---- staging ----
  if (PREP) {
    for (int t = tid; t < (ND * ND) / 8; t += 256) {   // 2048 x 16B vector copies
      const int row = t >> 4, cg = (t & 15) << 3;
      *reinterpret_cast<bf16x8*>(&w1T[row * KSTR + cg]) =
          *reinterpret_cast<const bf16x8*>(&w1f[row * ND + cg]);
    }
    if (tid < ND) b1p[tid] = b1pw[tid];
    for (int j = tid; j < NL; j += 256) notpad[j] = npadw[bb * NL + j];
  } else {
    for (int idx = tid; idx < ND * ND; idx += 256) {
      const int k = idx >> 7, n = idx & (ND - 1);
      w1T[n * KSTR + k] = f2bf(w1[idx] * ln_g[k]);
    }
    if (tid < ND) {
      float s = b1[tid];
      for (int k = 0; k < ND; ++k) s = fmaf(ln_b[k], w1[k * ND + tid], s);
      b1p[tid] = s;
    }
    for (int j = tid; j < NL; j += 256) notpad[j] = (nodes[bb * NL + j] != 0) ? 1.0f : 0.0f;
  }
  for (int j = tid; j < NL * 3; j += 256) coord_s[j] = coord[bb * (NL * 3) + j];
  __syncthreads();

  if (!PREP && tid < 64) {  // wave0: atom_num (consumed only after the final barrier)
    float s = 0.f;
    for (int j = tid; j < NL; j += 64) s += notpad[j];
    #pragma unroll
    for (int m = 1; m <= 32; m <<= 1) s += __shfl_xor(s, m);
    if (tid == 0) inv_atom_s = 1.0f / s;
  }

  const int lane = tid & 63;
  const int wv = tid >> 6;
  const int c = lane & 15;   // A-row within tile / D-column within tile
  const int g = lane >> 4;   // k-group
  float b1r[8], w2r[8];
  #pragma unroll
  for (int nt = 0; nt < 8; ++nt) { b1r[nt] = b1p[16 * nt + c]; w2r[nt] = w2[16 * nt + c]; }
  const float b2c = b2[0] * (1.0f / 16.0f);   // b2 split across the 16 c-lanes

  float s0 = 0.f, sx = 0.f, sy = 0.f, sz = 0.f;
  const size_t xbase = (size_t)(bb * NL + lrow) * (NL * ND);

  for (int it = 0; it < 8; ++it) {
    const int mbase = (it << 6) + (wv << 4);
    // lane's slice of 16 rows of x, directly in A-fragment layout:
    // row = c, k = 8*g + 32*ks + j
    const float* xr = x + xbase + (size_t)(mbase + c) * ND + 8 * g;
    f32x4 xv[8];
    #pragma unroll
    for (int ks = 0; ks < 4; ++ks) {
      xv[2 * ks]     = *reinterpret_cast<const f32x4*>(xr + 32 * ks);
      xv[2 * ks + 1] = *reinterpret_cast<const f32x4*>(xr + 32 * ks + 4);
    }
    // LayerNorm stats: 4 lanes (c, g=0..3) share one row -> xor 16, 32
    float sum = 0.f, sq = 0.f;
    #pragma unroll
    for (int q = 0; q < 8; ++q) {
      #pragma unroll
      for (int j = 0; j < 4; ++j) { const float e = xv[q][j]; sum += e; sq = fmaf(e, e, sq); }
    }
    sum += __shfl_xor(sum, 16); sum += __shfl_xor(sum, 32);
    sq  += __shfl_xor(sq, 16);  sq  += __shfl_xor(sq, 32);
    const float mu = sum * (1.0f / ND);
    const float rs = rsqrtf(fmaf(-mu, mu, sq * (1.0f / ND)) + 1e-5f);
    const float nmr = -mu * rs;

    bf16x8 af[4];
    #pragma unroll
    for (int ks = 0; ks < 4; ++ks) {
      #pragma unroll
      for (int j = 0; j < 8; ++j) {
        const float e = (j < 4) ? xv[2 * ks][j] : xv[2 * ks + 1][j - 4];
        af[ks][j] = f2bf(fmaf(e, rs, nmr));
      }
    }

    f32x4 acc[8];
    #pragma unroll
    for (int nt = 0; nt < 8; ++nt) acc[nt] = (f32x4){0.f, 0.f, 0.f, 0.f};
    #pragma unroll
    for (int ks = 0; ks < 4; ++ks) {
      const int koff = 8 * g + 32 * ks;
      #pragma unroll
      for (int nt = 0; nt < 8; ++nt) {
        const bf16x8 bf = *reinterpret_cast<const bf16x8*>(&w1T[(16 * nt + c) * KSTR + koff]);
        acc[nt] = __builtin_amdgcn_mfma_f32_16x16x32_bf16(af[ks], bf, acc[nt], 0, 0, 0);
      }
    }

    // epilogue: +b1, GELU, dot w2 -- keep per-lane PARTIAL sums (no shfl here);
    // the end-of-block reduction finishes the 16-lane n-sum for free.
    float p[4] = {0.f, 0.f, 0.f, 0.f};
    #pragma unroll
    for (int nt = 0; nt < 8; ++nt) {
      #pragma unroll
      for (int i = 0; i < 4; ++i) {
        const float h = acc[nt][i] + b1r[nt];
        p[i] = fmaf(gelu_exact(h), w2r[nt], p[i]);
      }
    }
    #pragma unroll
    for (int i = 0; i < 4; ++i) {
      const int m = mbase + 4 * g + i;        // D-layout row for this lane
      const float a = (p[i] + b2c) * notpad[m];
      s0 += a;
      sx = fmaf(a, coord_s[3 * m + 0], sx);
      sy = fmaf(a, coord_s[3 * m + 1], sy);
      sz = fmaf(a, coord_s[3 * m + 2], sz);
    }
  }

  #pragma unroll
  for (int m = 1; m <= 32; m <<= 1) {
    s0 += __shfl_xor(s0, m); sx += __shfl_xor(sx, m);
    sy += __shfl_xor(sy, m); sz += __shfl_xor(sz, m);
  }
  if (lane == 0) {
    red[wv * 4 + 0] = s0; red[wv * 4 + 1] = sx;
    red[wv * 4 + 2] = sy; red[wv * 4 + 3] = sz;
  }
  __syncthreads();
  if (tid == 0) {
    const float S0 = red[0] + red[4] + red[8] + red[12];
    const float SX = red[1] + red[5] + red[9] + red[13];
    const float SY = red[2] + red[6] + red[10] + red[14];
    const float SZ = red[3] + red[7] + red[11] + red[15];
    const float ia = PREP ? invw[bb] : inv_atom_s;
    const float cx = coord_s[3 * lrow + 0], cy = coord_s[3 * lrow + 1], cz = coord_s[3 * lrow + 2];
    float* o = out + (bb * NL + lrow) * 3;
    o[0] = cx + (SX - S0 * cx) * ia;
    o[1] = cy + (SY - S0 * cy) * ia;
    o[2] = cz + (SZ - S0 * cz) * ia;
  }
}

extern "C" void kernel_launch(void* const* d_in, const int* in_sizes, int n_in,
                              void* d_out, int out_size, void* d_ws, size_t ws_size,
                              hipStream_t stream) {
  const float* x     = (const float*)d_in[0];
  const float* coord = (const float*)d_in[1];
  const int*   nodes = (const int*)d_in[2];
  const float* ln_g  = (const float*)d_in[3];
  const float* ln_b  = (const float*)d_in[4];
  const float* w1    = (const float*)d_in[5];
  const float* b1    = (const float*)d_in[6];
  const float* w2    = (const float*)d_in[7];
  const float* b2    = (const float*)d_in[8];
  float* out = (float*)d_out;

  const size_t need = 32768 + 512 + 8192 + 16;
  if (ws_size >= need) {
    short* w1f  = (short*)d_ws;
    float* b1p  = (float*)((char*)d_ws + 32768);
    float* npad = (float*)((char*)d_ws + 33280);
    float* inva = (float*)((char*)d_ws + 41472);
    hipLaunchKernelGGL(unimol_prep, dim3(1), dim3(256), 0, stream,
                       w1, ln_g, ln_b, b1, nodes, w1f, b1p, npad, inva);
    hipLaunchKernelGGL((unimol_coord_head<true>), dim3(NB * NL), dim3(256), 0, stream,
                       x, coord, nodes, ln_g, ln_b, w1, b1, w2, b2,
                       w1f, b1p, npad, inva, out);
  } else {
    hipLaunchKernelGGL((unimol_coord_head<false>), dim3(NB * NL), dim3(256), 0, stream,
                       x, coord, nodes, ln_g, ln_b, w1, b1, w2, b2,
                       (const short*)nullptr, (const float*)nullptr,
                       (const float*)nullptr, (const float*)nullptr, out);
  }
}

// Round 3
// 191.066 us; speedup vs baseline: 2.0203x; 2.0203x over previous
//
#include <hip/hip_runtime.h>
#include <hip/hip_bf16.h>
#include <math.h>

#define NB 4
#define NL 512
#define ND 128
#define KSTR 136  // 128 + 8 bf16 pad -> 272B row stride, 16B aligned, 2-way banks (free)

typedef __attribute__((ext_vector_type(8))) short bf16x8;
typedef __attribute__((ext_vector_type(4))) float f32x4;

__device__ __forceinline__ short f2bf(float f) {
  union { float f; unsigned u; } un; un.f = f;
  unsigned r = un.u + 0x7FFFu + ((un.u >> 16) & 1u);  // RNE
  return (short)(r >> 16);
}

// exact-GELU via Abramowitz-Stegun 7.1.26 erf (max err 1.5e-7), branchless.
__device__ __forceinline__ float gelu_exact(float h) {
  const float z = 0.70710678118f * h;
  const float az = fabsf(z);
  const float t = __builtin_amdgcn_rcpf(fmaf(0.3275911f, az, 1.0f));
  float p = fmaf(1.061405429f, t, -1.453152027f);
  p = fmaf(p, t, 1.421413741f);
  p = fmaf(p, t, -0.284496736f);
  p = fmaf(p, t, 0.254829592f);
  p = p * t;
  const float ex = exp2f(az * az * -1.4426950408f);  // e^{-z^2}
  const float e = fmaf(-p, ex, 1.0f);                // erf(|z|)
  const float se = copysignf(e, z);
  const float hh = 0.5f * h;
  return fmaf(hh, se, hh);                            // 0.5h(1+erf(z))
}

// one-time weight prep into d_ws: gamma-folded bf16 w1 [n][k], beta-folded b1,
// notpad floats, per-batch 1/atom_num
__global__ void unimol_prep(const float* __restrict__ w1, const float* __restrict__ ln_g,
                            const float* __restrict__ ln_b, const float* __restrict__ b1,
                            const int* __restrict__ nodes,
                            short* __restrict__ w1f, float* __restrict__ b1p,
                            float* __restrict__ npad, float* __restrict__ inva) {
  const int tid = threadIdx.x;
  for (int idx = tid; idx < ND * ND; idx += 256) {
    const int k = idx >> 7, n = idx & (ND - 1);
    w1f[n * ND + k] = f2bf(w1[idx] * ln_g[k]);
  }
  if (tid < ND) {
    float s = b1[tid];
    for (int k = 0; k < ND; ++k) s = fmaf(ln_b[k], w1[k * ND + tid], s);
    b1p[tid] = s;
  }
  for (int j = tid; j < NB * NL; j += 256) npad[j] = (nodes[j] != 0) ? 1.0f : 0.0f;
  const int wv = tid >> 6, lane = tid & 63;
  if (wv < NB) {
    float s = 0.f;
    for (int j = lane; j < NL; j += 64) s += (nodes[wv * NL + j] != 0) ? 1.0f : 0.0f;
    #pragma unroll
    for (int m = 1; m <= 32; m <<= 1) s += __shfl_xor(s, m);
    if (lane == 0) inva[wv] = 1.0f / s;
  }
}

__global__ __launch_bounds__(256, 2) void unimol_coord_head(
    const float* __restrict__ x, const float* __restrict__ coord,
    const int* __restrict__ nodes, const float* __restrict__ w2,
    const float* __restrict__ b2,
    const short* __restrict__ w1f, const float* __restrict__ b1pw,
    const float* __restrict__ npadw, const float* __restrict__ invw,
    float* __restrict__ out)
{
  __shared__ __align__(16) short w1T[ND * KSTR];  // [n][k] bf16, gamma-folded
  __shared__ float b1p[ND];
  __shared__ float notpad[NL];
  __shared__ float coord_s[NL * 3];
  __shared__ float red[16];

  const int blk = blockIdx.x;
  const int bb = blk >> 9;
  const int lrow = blk & (NL - 1);
  const int tid = threadIdx.x;

  // pad row l: output = coord, contribution zero
  if (nodes[bb * NL + lrow] == 0) {
    if (tid < 3) out[(bb * NL + lrow) * 3 + tid] = coord[(bb * NL + lrow) * 3 + tid];
    return;
  }

  // ---- staging (vector copies from prepped workspace) ----
  for (int t = tid; t < (ND * ND) / 8; t += 256) {   // 2048 x 16B vector copies
    const int row = t >> 4, cg = (t & 15) << 3;
    *reinterpret_cast<bf16x8*>(&w1T[row * KSTR + cg]) =
        *reinterpret_cast<const bf16x8*>(&w1f[row * ND + cg]);
  }
  if (tid < ND) b1p[tid] = b1pw[tid];
  for (int j = tid; j < NL; j += 256) notpad[j] = npadw[bb * NL + j];
  for (int j = tid; j < NL * 3; j += 256) coord_s[j] = coord[bb * (NL * 3) + j];
  __syncthreads();

  const int lane = tid & 63;
  const int wv = tid >> 6;
  const int c = lane & 15;   // A-row within tile / D-column within tile
  const int g = lane >> 4;   // k-group
  float b1r[8], w2r[8];
  #pragma unroll
  for (int nt = 0; nt < 8; ++nt) { b1r[nt] = b1p[16 * nt + c]; w2r[nt] = w2[16 * nt + c]; }
  const float b2c = b2[0] * (1.0f / 16.0f);   // b2 split across the 16 c-lanes

  float s0 = 0.f, sx = 0.f, sy = 0.f, sz = 0.f;
  const size_t xbase = (size_t)(bb * NL + lrow) * (NL * ND);

  for (int it = 0; it < 8; ++it) {
    const int mbase = (it << 6) + (wv << 4);
    // lane's slice of 16 rows of x, directly in A-fragment layout:
    // row = c, k = 8*g + 32*ks + j
    const float* xr = x + xbase + (size_t)(mbase + c) * ND + 8 * g;
    f32x4 xv[8];
    #pragma unroll
    for (int ks = 0; ks < 4; ++ks) {
      xv[2 * ks]     = *reinterpret_cast<const f32x4*>(xr + 32 * ks);
      xv[2 * ks + 1] = *reinterpret_cast<const f32x4*>(xr + 32 * ks + 4);
    }
    // LayerNorm stats: 4 lanes (c, g=0..3) share one row -> xor 16, 32
    float sum = 0.f, sq = 0.f;
    #pragma unroll
    for (int q = 0; q < 8; ++q) {
      #pragma unroll
      for (int j = 0; j < 4; ++j) { const float e = xv[q][j]; sum += e; sq = fmaf(e, e, sq); }
    }
    sum += __shfl_xor(sum, 16); sum += __shfl_xor(sum, 32);
    sq  += __shfl_xor(sq, 16);  sq  += __shfl_xor(sq, 32);
    const float mu = sum * (1.0f / ND);
    const float rs = rsqrtf(fmaf(-mu, mu, sq * (1.0f / ND)) + 1e-5f);
    const float nmr = -mu * rs;

    bf16x8 af[4];
    #pragma unroll
    for (int ks = 0; ks < 4; ++ks) {
      #pragma unroll
      for (int j = 0; j < 8; ++j) {
        const float e = (j < 4) ? xv[2 * ks][j] : xv[2 * ks + 1][j - 4];
        af[ks][j] = f2bf(fmaf(e, rs, nmr));
      }
    }

    f32x4 acc[8];
    #pragma unroll
    for (int nt = 0; nt < 8; ++nt) acc[nt] = (f32x4){0.f, 0.f, 0.f, 0.f};
    #pragma unroll
    for (int ks = 0; ks < 4; ++ks) {
      const int koff = 8 * g + 32 * ks;
      #pragma unroll
      for (int nt = 0; nt < 8; ++nt) {
        const bf16x8 bf = *reinterpret_cast<const bf16x8*>(&w1T[(16 * nt + c) * KSTR + koff]);
        acc[nt] = __builtin_amdgcn_mfma_f32_16x16x32_bf16(af[ks], bf, acc[nt], 0, 0, 0);
      }
    }

    // epilogue: +b1, GELU, dot w2 -- per-lane PARTIAL sums (no shfl here);
    // the end-of-block reduction finishes the 16-lane n-sum for free.
    float p[4] = {0.f, 0.f, 0.f, 0.f};
    #pragma unroll
    for (int nt = 0; nt < 8; ++nt) {
      #pragma unroll
      for (int i = 0; i < 4; ++i) {
        const float h = acc[nt][i] + b1r[nt];
        p[i] = fmaf(gelu_exact(h), w2r[nt], p[i]);
      }
    }
    #pragma unroll
    for (int i = 0; i < 4; ++i) {
      const int m = mbase + 4 * g + i;        // D-layout row for this lane
      const float a = (p[i] + b2c) * notpad[m];
      s0 += a;
      sx = fmaf(a, coord_s[3 * m + 0], sx);
      sy = fmaf(a, coord_s[3 * m + 1], sy);
      sz = fmaf(a, coord_s[3 * m + 2], sz);
    }
  }

  #pragma unroll
  for (int m = 1; m <= 32; m <<= 1) {
    s0 += __shfl_xor(s0, m); sx += __shfl_xor(sx, m);
    sy += __shfl_xor(sy, m); sz += __shfl_xor(sz, m);
  }
  if (lane == 0) {
    red[wv * 4 + 0] = s0; red[wv * 4 + 1] = sx;
    red[wv * 4 + 2] = sy; red[wv * 4 + 3] = sz;
  }
  __syncthreads();
  if (tid == 0) {
    const float S0 = red[0] + red[4] + red[8] + red[12];
    const float SX = red[1] + red[5] + red[9] + red[13];
    const float SY = red[2] + red[6] + red[10] + red[14];
    const float SZ = red[3] + red[7] + red[11] + red[15];
    const float ia = invw[bb];
    const float cx = coord_s[3 * lrow + 0], cy = coord_s[3 * lrow + 1], cz = coord_s[3 * lrow + 2];
    float* o = out + (bb * NL + lrow) * 3;
    o[0] = cx + (SX - S0 * cx) * ia;
    o[1] = cy + (SY - S0 * cy) * ia;
    o[2] = cz + (SZ - S0 * cz) * ia;
  }
}

extern "C" void kernel_launch(void* const* d_in, const int* in_sizes, int n_in,
                              void* d_out, int out_size, void* d_ws, size_t ws_size,
                              hipStream_t stream) {
  const float* x     = (const float*)d_in[0];
  const float* coord = (const float*)d_in[1];
  const int*   nodes = (const int*)d_in[2];
  const float* ln_g  = (const float*)d_in[3];
  const float* ln_b  = (const float*)d_in[4];
  const float* w1    = (const float*)d_in[5];
  const float* b1    = (const float*)d_in[6];
  const float* w2    = (const float*)d_in[7];
  const float* b2    = (const float*)d_in[8];
  float* out = (float*)d_out;

  short* w1f  = (short*)d_ws;
  float* b1p  = (float*)((char*)d_ws + 32768);
  float* npad = (float*)((char*)d_ws + 33280);
  float* inva = (float*)((char*)d_ws + 41472);
  hipLaunchKernelGGL(unimol_prep, dim3(1), dim3(256), 0, stream,
                     w1, ln_g, ln_b, b1, nodes, w1f, b1p, npad, inva);
  hipLaunchKernelGGL(unimol_coord_head, dim3(NB * NL), dim3(256), 0, stream,
                     x, coord, nodes, w2, b2, w1f, b1p, npad, inva, out);
}